// Round 7
// baseline (453.315 us; speedup 1.0000x reference)
//
#include <hip/hip_runtime.h>
#include <hip/hip_bf16.h>
#include <math.h>

#define N_NODES 50000
#define DIN     128
#define DOUT    128
#define EPS_    1e-6f
#define N_WAVES 3125         // N_NODES / 16 rows per wave (exact)
#define NBKT    196          // coarse buckets: dst>>8 (256 nodes each)
#define EPB     4096         // edges per bucketA role (round-2/5 proven)
#define EPT     16           // edges per thread in bucketA
#define SLOT_CAP 5120        // records per bucket slot (avg 4082, +16 sigma)
#define NB_PROJ 782          // ceil(3125/4) proj roles
#define GRID    640          // mega grid: <= 768 guaranteed-resident (3/CU via launch_bounds)

typedef __attribute__((ext_vector_type(8))) short  bf16x8;
typedef __attribute__((ext_vector_type(4))) float  f32x4;
typedef unsigned short ushort_t;

__device__ __forceinline__ ushort_t f2bf(float f) {
    unsigned u = __float_as_uint(f);
    return (ushort_t)((u + 0x7fffu + ((u >> 16) & 1u)) >> 16);
}
__device__ __forceinline__ float bflo(unsigned u) { return __uint_as_float(u << 16); }
__device__ __forceinline__ float bfhi(unsigned u) { return __uint_as_float(u & 0xffff0000u); }

// Software grid barrier: one arrival counter per barrier site (no reuse, so no
// sense reversal). __threadfence() on gfx950 emits the cross-XCD L2
// writeback/invalidate; atomicAdd spins are device-scope coherent. Safe under
// plain launch because GRID=640 <= 768 guaranteed-co-resident blocks.
__device__ __forceinline__ void gbar(int* ctr) {
    __syncthreads();
    if (threadIdx.x == 0) {
        __threadfence();
        atomicAdd(ctr, 1);
        while (atomicAdd(ctr, 0) < GRID) __builtin_amdgcn_s_sleep(4);
        __threadfence();
    }
    __syncthreads();
}

// ---------------------------------------------------------------------------
// Mega kernel (replaces prep_w + fused_projA + place: 3 dispatches -> 1).
// R6 failed because hipLaunchCooperativeKernel was not enqueued under graph
// capture (output stayed zero); this uses a plain launch + manual barrier.
//   phase 0: W-frag pack (blocks 0..63) + gcur zero (block 64)
//   gbar
//   phase 1: 978 roles via atomic work queue: role<nA -> bucketA, else proj
//   gbar
//   phase 2: blocks [0,196) fine counting sort per bucket (LDS-staged)
// bar[0]=arrive1, bar[1]=arrive2, bar[2]=work queue cursor (memset to 0).
// ---------------------------------------------------------------------------
__global__ __launch_bounds__(256, 3) void mega_kernel(
    const float* __restrict__ mean, const float* __restrict__ var,
    const float* __restrict__ Wm,   const float* __restrict__ bm,
    const float* __restrict__ Wv,   const float* __restrict__ bv,
    const int* __restrict__ src, const int* __restrict__ dst,
    const float* __restrict__ w0, const float* __restrict__ w1,
    ushort_t* __restrict__ mv, ushort_t* __restrict__ wfm, ushort_t* __restrict__ wfv,
    int* __restrict__ gcur, uint2* __restrict__ slots,
    uint2* __restrict__ final_e, int* __restrict__ node_start,
    int* __restrict__ bar, int E, int nA)
{
    __shared__ uint2 s_rec[EPB];                                       // 32 KB
    __shared__ int   s_hist[256], s_scn[256], s_cur[256], s_base[256]; // 4 KB
    __shared__ int   s_role;

    const int t = threadIdx.x;
    const int b = blockIdx.x;

    // ------------------- phase 0: W pack + cursor zero -------------------
    {
        const int gid = b * 256 + t;
        if (gid < DIN * DOUT) {                    // blocks 0..63
            const int k = gid >> 7, n = gid & 127;
            const int ct = n >> 4, kk = k >> 5, quad = (k >> 3) & 3, j = k & 7;
            const int idx = ((ct * 4 + kk) * 64 + quad * 16 + (n & 15)) * 8 + j;
            wfm[idx] = f2bf(Wm[gid]);
            wfv[idx] = f2bf(Wv[gid]);
        }
        if (b == 64 && t < NBKT) gcur[t] = 0;
    }
    gbar(&bar[0]);

    // ------------------- phase 1: dynamic roles: bucketA / proj ----------
    const int nRoles = nA + NB_PROJ;
    for (;;) {
        __syncthreads();                 // protects s_role and LDS reuse
        if (t == 0) s_role = atomicAdd(&bar[2], 1);
        __syncthreads();
        const int role = s_role;
        if (role >= nRoles) break;

        if (role < nA) {
            // ---------- bucketA role (round-5 proven body) ----------
            const int e0 = role * EPB;
            const int n  = min(EPB, E - e0);

            s_hist[t] = 0;
            __syncthreads();

            int   myb[EPT];
            uint2 myr[EPT];
#pragma unroll
            for (int j = 0; j < EPT; ++j) {
                const int e = e0 + t + j * 256;
                if (e < E) {
                    const int d   = dst[e];
                    const int bkt = d >> 8;
                    myb[j] = bkt;
                    myr[j].x = (unsigned)src[e] | ((unsigned)(d & 255) << 16)
                             | ((unsigned)bkt << 24);
                    myr[j].y = (unsigned)f2bf(w0[e]) | ((unsigned)f2bf(w1[e]) << 16);
                    atomicAdd(&s_hist[bkt], 1);
                } else myb[j] = -1;
            }
            __syncthreads();

            if (t < NBKT) {
                const int c = s_hist[t];
                s_base[t] = t * SLOT_CAP + (c ? atomicAdd(&gcur[t], c) : 0);
            }
            const int x = s_hist[t];
            s_scn[t] = x;
            __syncthreads();
            for (int off = 1; off < 256; off <<= 1) {
                const int v = (t >= off) ? s_scn[t - off] : 0;
                __syncthreads();
                s_scn[t] += v;
                __syncthreads();
            }
            const int excl = s_scn[t] - x;
            __syncthreads();
            s_scn[t] = excl;
            s_cur[t] = 0;
            __syncthreads();

#pragma unroll
            for (int j = 0; j < EPT; ++j) {
                if (myb[j] >= 0) {
                    const int r = atomicAdd(&s_cur[myb[j]], 1);
                    s_rec[s_scn[myb[j]] + r] = myr[j];
                }
            }
            __syncthreads();

            for (int i = t; i < n; i += 256) {
                const uint2 r = s_rec[i];
                const int bkt = r.x >> 24;
                slots[s_base[bkt] + (i - s_scn[bkt])] = r;
            }
        } else {
            // ---------- proj role (round-5 proven body) ----------
            const int wave = (role - nA) * 4 + (t >> 6);
            if (wave < N_WAVES) {
                const int lane = t & 63;
                const int row0 = wave * 16;
                const int kq   = lane >> 4;
                const int arow = row0 + (lane & 15);

                f32x4 accm[8], accv[8];
#pragma unroll
                for (int ct = 0; ct < 8; ++ct) {
                    accm[ct] = (f32x4){0.f, 0.f, 0.f, 0.f};
                    accv[ct] = (f32x4){0.f, 0.f, 0.f, 0.f};
                }

                const float* mrow = mean + (size_t)arow * DIN;
                const float* vrow = var  + (size_t)arow * DIN;

#pragma unroll
                for (int kk = 0; kk < 4; ++kk) {
                    const int kb = kk * 32 + kq * 8;
                    const float4 am0 = *(const float4*)(mrow + kb);
                    const float4 am1 = *(const float4*)(mrow + kb + 4);
                    const float4 av0 = *(const float4*)(vrow + kb);
                    const float4 av1 = *(const float4*)(vrow + kb + 4);
                    bf16x8 a_m, a_v;
                    a_m[0]=f2bf(am0.x); a_m[1]=f2bf(am0.y); a_m[2]=f2bf(am0.z); a_m[3]=f2bf(am0.w);
                    a_m[4]=f2bf(am1.x); a_m[5]=f2bf(am1.y); a_m[6]=f2bf(am1.z); a_m[7]=f2bf(am1.w);
                    a_v[0]=f2bf(av0.x); a_v[1]=f2bf(av0.y); a_v[2]=f2bf(av0.z); a_v[3]=f2bf(av0.w);
                    a_v[4]=f2bf(av1.x); a_v[5]=f2bf(av1.y); a_v[6]=f2bf(av1.z); a_v[7]=f2bf(av1.w);

#pragma unroll
                    for (int ct = 0; ct < 8; ++ct) {
                        const bf16x8 b_m = *(const bf16x8*)(wfm + ((size_t)(ct * 4 + kk) * 64 + lane) * 8);
                        const bf16x8 b_v = *(const bf16x8*)(wfv + ((size_t)(ct * 4 + kk) * 64 + lane) * 8);
                        accm[ct] = __builtin_amdgcn_mfma_f32_16x16x32_bf16(a_m, b_m, accm[ct], 0, 0, 0);
                        accv[ct] = __builtin_amdgcn_mfma_f32_16x16x32_bf16(a_v, b_v, accv[ct], 0, 0, 0);
                    }
                }

                const int par = lane & 1;
#pragma unroll
                for (int ct = 0; ct < 8; ++ct) {
                    const int col = ct * 16 + (lane & 15);
                    const float bmc = bm[col];
                    const float bvc = bv[col];
                    const int dw = ct * 16 + ((lane & 15) >> 1) * 2 + par;
#pragma unroll
                    for (int r = 0; r < 4; ++r) {
                        const int row = row0 + kq * 4 + r;
                        float m = accm[ct][r] + bmc;
                        m = (m > 0.0f) ? m : (expf(m) - 1.0f);           // ELU
                        float v = accv[ct][r] + bvc;
                        v = ((v > 0.0f) ? v : 0.0f) + EPS_;              // ReLU + eps
                        const float att = expf(-v);
                        const unsigned um = f2bf(m * att);
                        const unsigned uv = f2bf(v * att * att);
                        const unsigned om = (unsigned)__shfl_xor((int)um, 1);
                        const unsigned ov = (unsigned)__shfl_xor((int)uv, 1);
                        const unsigned w = par ? (ov | (uv << 16)) : (um | (om << 16));
                        ((unsigned*)(mv + (size_t)row * 256))[dw] = w;
                    }
                }
            }
        }
    }
    gbar(&bar[1]);

    // ------------------- phase 2: fine counting sort per bucket ----------
    if (b < NBKT) {
        s_base[t] = (t < b) ? gcur[t] : 0;   // reduce buffer
        s_hist[t] = 0;
        __syncthreads();

        const int cnt = gcur[b];
        const uint2* slot = slots + (size_t)b * SLOT_CAP;

        // single global pass: stage first EPB records in LDS + histogram all
        for (int i = t; i < cnt; i += 256) {
            const uint2 r = slot[i];
            if (i < EPB) s_rec[i] = r;
            atomicAdd(&s_hist[(r.x >> 16) & 255], 1);
        }
        __syncthreads();

        for (int off = 128; off > 0; off >>= 1) {
            if (t < off) s_base[t] += s_base[t + off];
            __syncthreads();
        }
        const int base = s_base[0];

        const int x = s_hist[t];
        s_scn[t] = x;
        __syncthreads();
        for (int off = 1; off < 256; off <<= 1) {
            const int v = (t >= off) ? s_scn[t - off] : 0;
            __syncthreads();
            s_scn[t] += v;
            __syncthreads();
        }
        const int ns = base + s_scn[t] - x;
        const int gidx = b * 256 + t;
        if (gidx <= N_NODES) node_start[gidx] = ns;
        s_cur[t] = ns;
        __syncthreads();

        // place: staged records from LDS, overflow tail (cnt>EPB) from L2
        for (int i = t; i < cnt; i += 256) {
            const uint2 r = (i < EPB) ? s_rec[i] : slot[i];
            const int f = (r.x >> 16) & 255;
            const int p = atomicAdd(&s_cur[f], 1);
            final_e[p] = r;
        }
    }
}

// ---------------------------------------------------------------------------
// agg kernel: exact round-0/5 form (proven 59us, occ 68%).
// ---------------------------------------------------------------------------
#define PAIR_FMA(RW, G) do {                                                 \
    const float a0 = bflo(RW), a1 = bfhi(RW);                                \
    am0 = fmaf(a0, bflo((G).x), am0); am1 = fmaf(a0, bfhi((G).x), am1);      \
    av0 = fmaf(a1, bflo((G).y), av0); av1 = fmaf(a1, bfhi((G).y), av1);      \
    am2 = fmaf(a0, bflo((G).z), am2); am3 = fmaf(a0, bfhi((G).z), am3);      \
    av2 = fmaf(a1, bflo((G).w), av2); av3 = fmaf(a1, bfhi((G).w), av3);      \
} while (0)

__global__ __launch_bounds__(256) void agg_kernel(
    const ushort_t* __restrict__ mv,
    const uint2* __restrict__ edges, const int* __restrict__ node_start,
    float* __restrict__ out_m, float* __restrict__ out_v)
{
    const int node = blockIdx.x * 4 + (threadIdx.x >> 6);
    const int lane = threadIdx.x & 63;
    const int half = lane >> 5;
    const int l    = lane & 31;
    if (node >= N_NODES) return;

    const int j0 = node_start[node];
    const int j1 = node_start[node + 1];

    float am0=0.f, am1=0.f, am2=0.f, am3=0.f;
    float av0=0.f, av1=0.f, av2=0.f, av3=0.f;

    int j = j0;

    if ((j & 1) && j < j1) {
        const uint2 r = edges[j];
        const unsigned rw = half ? 0u : r.y;
        const uint4 g = *(const uint4*)(mv + (size_t)(r.x & 0xffffu) * 256 + l * 8);
        PAIR_FMA(rw, g);
        ++j;
    }

    for (; j + 8 <= j1; j += 8) {
        const uint4 e0 = *(const uint4*)(edges + j + 0);
        const uint4 e1 = *(const uint4*)(edges + j + 2);
        const uint4 e2 = *(const uint4*)(edges + j + 4);
        const uint4 e3 = *(const uint4*)(edges + j + 6);
        const unsigned s0 = half ? e0.z : e0.x, w0 = half ? e0.w : e0.y;
        const unsigned s1 = half ? e1.z : e1.x, w1 = half ? e1.w : e1.y;
        const unsigned s2 = half ? e2.z : e2.x, w2 = half ? e2.w : e2.y;
        const unsigned s3 = half ? e3.z : e3.x, w3 = half ? e3.w : e3.y;
        const uint4 g0 = *(const uint4*)(mv + (size_t)(s0 & 0xffffu) * 256 + l * 8);
        const uint4 g1 = *(const uint4*)(mv + (size_t)(s1 & 0xffffu) * 256 + l * 8);
        const uint4 g2 = *(const uint4*)(mv + (size_t)(s2 & 0xffffu) * 256 + l * 8);
        const uint4 g3 = *(const uint4*)(mv + (size_t)(s3 & 0xffffu) * 256 + l * 8);
        PAIR_FMA(w0, g0);
        PAIR_FMA(w1, g1);
        PAIR_FMA(w2, g2);
        PAIR_FMA(w3, g3);
    }

    for (; j + 2 <= j1; j += 2) {
        const uint4 e = *(const uint4*)(edges + j);
        const unsigned s = half ? e.z : e.x, w = half ? e.w : e.y;
        const uint4 g = *(const uint4*)(mv + (size_t)(s & 0xffffu) * 256 + l * 8);
        PAIR_FMA(w, g);
    }

    if (j < j1) {
        const uint2 r = edges[j];
        const unsigned rw = half ? 0u : r.y;
        const uint4 g = *(const uint4*)(mv + (size_t)(r.x & 0xffffu) * 256 + l * 8);
        PAIR_FMA(rw, g);
    }

    am0 += __shfl_xor(am0, 32); am1 += __shfl_xor(am1, 32);
    am2 += __shfl_xor(am2, 32); am3 += __shfl_xor(am3, 32);
    av0 += __shfl_xor(av0, 32); av1 += __shfl_xor(av1, 32);
    av2 += __shfl_xor(av2, 32); av3 += __shfl_xor(av3, 32);

    if (half == 0) {
        *(float4*)(out_m + (size_t)node * DOUT + l * 4) = make_float4(am0, am1, am2, am3);
        *(float4*)(out_v + (size_t)node * DOUT + l * 4) = make_float4(av0, av1, av2, av3);
    }
}

// ---------------------------------------------------------------------------
extern "C" void kernel_launch(void* const* d_in, const int* in_sizes, int n_in,
                              void* d_out, int out_size, void* d_ws, size_t ws_size,
                              hipStream_t stream) {
    const float* mean = (const float*)d_in[0];
    const float* var  = (const float*)d_in[1];
    const float* Wm   = (const float*)d_in[2];
    const float* bm   = (const float*)d_in[3];
    const float* Wv   = (const float*)d_in[4];
    const float* bv   = (const float*)d_in[5];
    const float* a0   = (const float*)d_in[6];
    const float* a1   = (const float*)d_in[7];
    const int*   es   = (const int*)d_in[8];
    const int*   ed   = (const int*)d_in[9];
    const int    E    = in_sizes[6];

    // Workspace layout (byte offsets, 16B-aligned; round-0 proven footprint):
    //   mv [N][256] bf16           0          .. 25,600,000
    //   slots uint2[196*5120]      25,600,000 .. 33,628,160
    //   final_e uint2[E]           33,628,160 .. 40,028,160
    //   node_start int[N+1]        40,028,160 .. 40,228,164
    //   gcur int[196]              40,228,176 .. 40,228,960
    //   bar int[4]                 40,228,960 .. 40,228,976  (pad reuse)
    //   wfm/wfv bf16 frags         40,228,976 .. 40,294,512
    char* ws = (char*)d_ws;
    ushort_t* mv        = (ushort_t*)ws;
    uint2* slots        = (uint2*)(ws + 25600000);
    uint2* final_e      = (uint2*)(ws + 33628160);
    int*   node_start   = (int*)  (ws + 40028160);
    int*   gcur         = (int*)  (ws + 40228176);
    int*   bar          = (int*)  (ws + 40228960);
    ushort_t* wfm       = (ushort_t*)(ws + 40228976);
    ushort_t* wfv       = wfm + 16384;

    float* out_m = (float*)d_out;
    float* out_v = out_m + (size_t)N_NODES * DOUT;

    const int nA = (E + EPB - 1) / EPB;

    hipMemsetAsync(bar, 0, 16, stream);   // arrive1, arrive2, queue cursor

    mega_kernel<<<GRID, 256, 0, stream>>>(
        mean, var, Wm, bm, Wv, bv,
        es, ed, a0, a1,
        mv, wfm, wfv,
        gcur, slots, final_e, node_start,
        bar, E, nA);

    agg_kernel<<<(N_NODES + 3) / 4, 256, 0, stream>>>(
        mv, final_e, node_start, out_m, out_v);
}

// Round 8
// 206.471 us; speedup vs baseline: 2.1955x; 2.1955x over previous
//
#include <hip/hip_runtime.h>
#include <hip/hip_bf16.h>
#include <math.h>

#define N_NODES 50000
#define DIN     128
#define DOUT    128
#define EPS_    1e-6f
#define N_WAVES 3125         // N_NODES / 16 rows per wave (exact)
#define NBKT    196          // coarse buckets: dst>>8 (256 nodes each)
#define EPB     4096         // edges per bucketA role (round-2/5 proven)
#define EPT     16           // edges per thread in bucketA
#define SLOT_CAP 5120        // records per bucket slot (avg 4082, +16 sigma)
#define NB_PROJ 782          // ceil(3125/4) proj blocks

typedef __attribute__((ext_vector_type(8))) short  bf16x8;
typedef __attribute__((ext_vector_type(4))) float  f32x4;
typedef unsigned short ushort_t;

__device__ __forceinline__ ushort_t f2bf(float f) {
    unsigned u = __float_as_uint(f);
    return (ushort_t)((u + 0x7fffu + ((u >> 16) & 1u)) >> 16);
}
__device__ __forceinline__ float bflo(unsigned u) { return __uint_as_float(u << 16); }
__device__ __forceinline__ float bfhi(unsigned u) { return __uint_as_float(u & 0xffff0000u); }

// ---------------------------------------------------------------------------
// Kernel 0: pre-pack Wm/Wv into bf16 B-fragment order; zero bucket cursors.
// (round-0/5 proven form)
// ---------------------------------------------------------------------------
__global__ __launch_bounds__(256) void prep_w_kernel(
    const float* __restrict__ Wm, const float* __restrict__ Wv,
    ushort_t* __restrict__ fm, ushort_t* __restrict__ fv,
    int* __restrict__ gcur)
{
    const int gid = blockIdx.x * 256 + threadIdx.x;   // 16384 threads
    if (gid < NBKT) gcur[gid] = 0;
    const int k = gid >> 7, n = gid & 127;
    const int ct = n >> 4, kk = k >> 5, quad = (k >> 3) & 3, j = k & 7;
    const int idx = ((ct * 4 + kk) * 64 + quad * 16 + (n & 15)) * 8 + j;
    fm[idx] = f2bf(Wm[gid]);
    fv[idx] = f2bf(Wv[gid]);
}

// ---------------------------------------------------------------------------
// Kernel 1 (FUSED): blocks [0,nA) run the coarse bucket sort (phase A);
// blocks [nA, nA+NB_PROJ) run the MFMA projection. Round-5 proven verbatim.
// Record word x packs: src[0:16) | fine[16:24) | coarse[24:32).
// ---------------------------------------------------------------------------
__global__ __launch_bounds__(256) void fused_projA_kernel(
    // proj args
    const float* __restrict__ mean, const float* __restrict__ var,
    const float* __restrict__ bm,   const float* __restrict__ bv,
    const ushort_t* __restrict__ wfm, const ushort_t* __restrict__ wfv,
    ushort_t* __restrict__ mv,
    // bucketA args
    const int* __restrict__ src, const int* __restrict__ dst,
    const float* __restrict__ w0, const float* __restrict__ w1,
    int* __restrict__ gcur, uint2* __restrict__ slots, int E, int nA)
{
    if ((int)blockIdx.x < nA) {
        // ------------------- bucketA role -------------------
        __shared__ uint2 s_rec[EPB];
        __shared__ int   s_hist[256];
        __shared__ int   s_scn[256];
        __shared__ int   s_cur[256];
        __shared__ int   s_base[256];

        const int t  = threadIdx.x;
        const int e0 = blockIdx.x * EPB;
        const int n  = min(EPB, E - e0);

        s_hist[t] = 0;
        __syncthreads();

        int   myb[EPT];
        uint2 myr[EPT];
#pragma unroll
        for (int j = 0; j < EPT; ++j) {
            const int e = e0 + t + j * 256;
            if (e < E) {
                const int d   = dst[e];
                const int bkt = d >> 8;
                myb[j] = bkt;
                myr[j].x = (unsigned)src[e] | ((unsigned)(d & 255) << 16)
                         | ((unsigned)bkt << 24);
                myr[j].y = (unsigned)f2bf(w0[e]) | ((unsigned)f2bf(w1[e]) << 16);
                atomicAdd(&s_hist[bkt], 1);
            } else myb[j] = -1;
        }
        __syncthreads();

        if (t < NBKT) {
            const int c = s_hist[t];
            s_base[t] = t * SLOT_CAP + (c ? atomicAdd(&gcur[t], c) : 0);
        }
        const int x = s_hist[t];
        s_scn[t] = x;
        __syncthreads();
        for (int off = 1; off < 256; off <<= 1) {
            const int v = (t >= off) ? s_scn[t - off] : 0;
            __syncthreads();
            s_scn[t] += v;
            __syncthreads();
        }
        const int excl = s_scn[t] - x;
        __syncthreads();
        s_scn[t] = excl;
        s_cur[t] = 0;
        __syncthreads();

#pragma unroll
        for (int j = 0; j < EPT; ++j) {
            if (myb[j] >= 0) {
                const int r = atomicAdd(&s_cur[myb[j]], 1);
                s_rec[s_scn[myb[j]] + r] = myr[j];
            }
        }
        __syncthreads();

        for (int i = t; i < n; i += 256) {
            const uint2 r = s_rec[i];
            const int bkt = r.x >> 24;
            slots[s_base[bkt] + (i - s_scn[bkt])] = r;
        }
        return;
    }

    // ------------------- proj role -------------------
    const int wave = ((int)blockIdx.x - nA) * 4 + (threadIdx.x >> 6);
    if (wave >= N_WAVES) return;
    const int lane = threadIdx.x & 63;
    const int row0 = wave * 16;
    const int kq   = lane >> 4;             // 0..3
    const int arow = row0 + (lane & 15);

    f32x4 accm[8], accv[8];
#pragma unroll
    for (int ct = 0; ct < 8; ++ct) {
        accm[ct] = (f32x4){0.f, 0.f, 0.f, 0.f};
        accv[ct] = (f32x4){0.f, 0.f, 0.f, 0.f};
    }

    const float* mrow = mean + (size_t)arow * DIN;
    const float* vrow = var  + (size_t)arow * DIN;

#pragma unroll
    for (int kk = 0; kk < 4; ++kk) {
        const int kb = kk * 32 + kq * 8;
        const float4 am0 = *(const float4*)(mrow + kb);
        const float4 am1 = *(const float4*)(mrow + kb + 4);
        const float4 av0 = *(const float4*)(vrow + kb);
        const float4 av1 = *(const float4*)(vrow + kb + 4);
        bf16x8 a_m, a_v;
        a_m[0]=f2bf(am0.x); a_m[1]=f2bf(am0.y); a_m[2]=f2bf(am0.z); a_m[3]=f2bf(am0.w);
        a_m[4]=f2bf(am1.x); a_m[5]=f2bf(am1.y); a_m[6]=f2bf(am1.z); a_m[7]=f2bf(am1.w);
        a_v[0]=f2bf(av0.x); a_v[1]=f2bf(av0.y); a_v[2]=f2bf(av0.z); a_v[3]=f2bf(av0.w);
        a_v[4]=f2bf(av1.x); a_v[5]=f2bf(av1.y); a_v[6]=f2bf(av1.z); a_v[7]=f2bf(av1.w);

#pragma unroll
        for (int ct = 0; ct < 8; ++ct) {
            const bf16x8 b_m = *(const bf16x8*)(wfm + ((size_t)(ct * 4 + kk) * 64 + lane) * 8);
            const bf16x8 b_v = *(const bf16x8*)(wfv + ((size_t)(ct * 4 + kk) * 64 + lane) * 8);
            accm[ct] = __builtin_amdgcn_mfma_f32_16x16x32_bf16(a_m, b_m, accm[ct], 0, 0, 0);
            accv[ct] = __builtin_amdgcn_mfma_f32_16x16x32_bf16(a_v, b_v, accv[ct], 0, 0, 0);
        }
    }

    // Epilogue: pack pairs of adjacent-column lanes into single dword stores.
    const int par = lane & 1;                       // col parity == lane parity
#pragma unroll
    for (int ct = 0; ct < 8; ++ct) {
        const int col = ct * 16 + (lane & 15);
        const float bmc = bm[col];
        const float bvc = bv[col];
        const int dw = ct * 16 + ((lane & 15) >> 1) * 2 + par;  // dword idx in 128-dword row
#pragma unroll
        for (int r = 0; r < 4; ++r) {
            const int row = row0 + kq * 4 + r;
            float m = accm[ct][r] + bmc;
            m = (m > 0.0f) ? m : (expf(m) - 1.0f);           // ELU
            float v = accv[ct][r] + bvc;
            v = ((v > 0.0f) ? v : 0.0f) + EPS_;              // ReLU + eps
            const float att = expf(-v);
            const unsigned um = f2bf(m * att);
            const unsigned uv = f2bf(v * att * att);
            const unsigned om = (unsigned)__shfl_xor((int)um, 1);
            const unsigned ov = (unsigned)__shfl_xor((int)uv, 1);
            // even lane: [m(c0) | m(c1)<<16]; odd lane: [v(c0) | v(c1)<<16]
            const unsigned w = par ? (ov | (uv << 16)) : (um | (om << 16));
            ((unsigned*)(mv + (size_t)row * 256))[dw] = w;
        }
    }
}

// ---------------------------------------------------------------------------
// Kernel 2: fine counting sort per bucket — 1024-thread, LDS-staged (R5),
// with uint4 staging this round: 2 records / 16B per thread per iteration
// halves the dependent load rounds and doubles bytes-in-flight (place is
// latency-bound at ~0.77 blocks/CU, not BW-bound).
// ---------------------------------------------------------------------------
__global__ __launch_bounds__(1024) void place_kernel(
    const int* __restrict__ gcur,
    const uint2* __restrict__ slots, uint2* __restrict__ final_e,
    int* __restrict__ node_start)
{
    __shared__ __attribute__((aligned(16))) uint2 s_rec[SLOT_CAP];
    __shared__ int s_hist[256];
    __shared__ int s_scn[256];
    __shared__ int s_cur[256];
    __shared__ int s_red[256];

    const int b = blockIdx.x;
    const int t = threadIdx.x;

    if (t < 256) {
        s_red[t]  = (t < b) ? gcur[t] : 0;
        s_hist[t] = 0;
    }
    __syncthreads();

    const int cnt = gcur[b];
    const uint2* slot = slots + (size_t)b * SLOT_CAP;

    // single global pass, 16B/thread: stage into LDS + histogram of fine key
    const int cnt2 = cnt & ~1;
    for (int i = t * 2; i < cnt2; i += 2048) {
        const uint4 r2 = *(const uint4*)(slot + i);
        *(uint4*)(s_rec + i) = r2;
        atomicAdd(&s_hist[(r2.x >> 16) & 255], 1);
        atomicAdd(&s_hist[(r2.z >> 16) & 255], 1);
    }
    if (t == 0 && cnt2 < cnt) {
        const uint2 r = slot[cnt2];
        s_rec[cnt2] = r;
        atomicAdd(&s_hist[(r.x >> 16) & 255], 1);
    }

    // base = sum gcur[0..b) on first 256 threads
    __syncthreads();
    if (t < 128) s_red[t] += s_red[t + 128];
    __syncthreads();
    if (t < 64)  s_red[t] += s_red[t + 64];
    __syncthreads();
    if (t < 32)  s_red[t] += s_red[t + 32];
    __syncthreads();
    if (t < 16)  s_red[t] += s_red[t + 16];
    __syncthreads();
    if (t < 8)   s_red[t] += s_red[t + 8];
    __syncthreads();
    if (t < 4)   s_red[t] += s_red[t + 4];
    __syncthreads();
    if (t < 2)   s_red[t] += s_red[t + 2];
    __syncthreads();
    if (t < 1)   s_red[t] += s_red[t + 1];
    __syncthreads();
    const int base = s_red[0];

    // exclusive scan of 256 fine bins (first 256 threads)
    const int x = (t < 256) ? s_hist[t] : 0;
    if (t < 256) s_scn[t] = x;
    __syncthreads();
    for (int off = 1; off < 256; off <<= 1) {
        int v = 0;
        if (t < 256 && t >= off) v = s_scn[t - off];
        __syncthreads();
        if (t < 256) s_scn[t] += v;
        __syncthreads();
    }
    if (t < 256) {
        const int ns = base + s_scn[t] - x;   // global start for node b*256+t
        const int gidx = b * 256 + t;
        if (gidx <= N_NODES) node_start[gidx] = ns;
        s_cur[t] = ns;
    }
    __syncthreads();

    // place from LDS (writes confined to this bucket's final_e region)
    for (int i = t; i < cnt; i += 1024) {
        const uint2 r = s_rec[i];
        const int f = (r.x >> 16) & 255;
        const int p = atomicAdd(&s_cur[f], 1);
        final_e[p] = r;
    }
}

// ---------------------------------------------------------------------------
// Kernel 3: gather aggregation — exact round-0/5 form (proven 59us, occ 68%,
// ~7.9 TB/s logical vector-memory flow = at the gather-path roofline).
// ---------------------------------------------------------------------------
#define PAIR_FMA(RW, G) do {                                                 \
    const float a0 = bflo(RW), a1 = bfhi(RW);                                \
    am0 = fmaf(a0, bflo((G).x), am0); am1 = fmaf(a0, bfhi((G).x), am1);      \
    av0 = fmaf(a1, bflo((G).y), av0); av1 = fmaf(a1, bfhi((G).y), av1);      \
    am2 = fmaf(a0, bflo((G).z), am2); am3 = fmaf(a0, bfhi((G).z), am3);      \
    av2 = fmaf(a1, bflo((G).w), av2); av3 = fmaf(a1, bfhi((G).w), av3);      \
} while (0)

__global__ __launch_bounds__(256) void agg_kernel(
    const ushort_t* __restrict__ mv,
    const uint2* __restrict__ edges, const int* __restrict__ node_start,
    float* __restrict__ out_m, float* __restrict__ out_v)
{
    const int node = blockIdx.x * 4 + (threadIdx.x >> 6);
    const int lane = threadIdx.x & 63;
    const int half = lane >> 5;
    const int l    = lane & 31;
    if (node >= N_NODES) return;

    const int j0 = node_start[node];
    const int j1 = node_start[node + 1];

    float am0=0.f, am1=0.f, am2=0.f, am3=0.f;
    float av0=0.f, av1=0.f, av2=0.f, av3=0.f;

    int j = j0;

    if ((j & 1) && j < j1) {
        const uint2 r = edges[j];
        const unsigned rw = half ? 0u : r.y;
        const uint4 g = *(const uint4*)(mv + (size_t)(r.x & 0xffffu) * 256 + l * 8);
        PAIR_FMA(rw, g);
        ++j;
    }

    for (; j + 8 <= j1; j += 8) {
        const uint4 e0 = *(const uint4*)(edges + j + 0);
        const uint4 e1 = *(const uint4*)(edges + j + 2);
        const uint4 e2 = *(const uint4*)(edges + j + 4);
        const uint4 e3 = *(const uint4*)(edges + j + 6);
        const unsigned s0 = half ? e0.z : e0.x, w0 = half ? e0.w : e0.y;
        const unsigned s1 = half ? e1.z : e1.x, w1 = half ? e1.w : e1.y;
        const unsigned s2 = half ? e2.z : e2.x, w2 = half ? e2.w : e2.y;
        const unsigned s3 = half ? e3.z : e3.x, w3 = half ? e3.w : e3.y;
        const uint4 g0 = *(const uint4*)(mv + (size_t)(s0 & 0xffffu) * 256 + l * 8);
        const uint4 g1 = *(const uint4*)(mv + (size_t)(s1 & 0xffffu) * 256 + l * 8);
        const uint4 g2 = *(const uint4*)(mv + (size_t)(s2 & 0xffffu) * 256 + l * 8);
        const uint4 g3 = *(const uint4*)(mv + (size_t)(s3 & 0xffffu) * 256 + l * 8);
        PAIR_FMA(w0, g0);
        PAIR_FMA(w1, g1);
        PAIR_FMA(w2, g2);
        PAIR_FMA(w3, g3);
    }

    for (; j + 2 <= j1; j += 2) {
        const uint4 e = *(const uint4*)(edges + j);
        const unsigned s = half ? e.z : e.x, w = half ? e.w : e.y;
        const uint4 g = *(const uint4*)(mv + (size_t)(s & 0xffffu) * 256 + l * 8);
        PAIR_FMA(w, g);
    }

    if (j < j1) {
        const uint2 r = edges[j];
        const unsigned rw = half ? 0u : r.y;
        const uint4 g = *(const uint4*)(mv + (size_t)(r.x & 0xffffu) * 256 + l * 8);
        PAIR_FMA(rw, g);
    }

    am0 += __shfl_xor(am0, 32); am1 += __shfl_xor(am1, 32);
    am2 += __shfl_xor(am2, 32); am3 += __shfl_xor(am3, 32);
    av0 += __shfl_xor(av0, 32); av1 += __shfl_xor(av1, 32);
    av2 += __shfl_xor(av2, 32); av3 += __shfl_xor(av3, 32);

    if (half == 0) {
        *(float4*)(out_m + (size_t)node * DOUT + l * 4) = make_float4(am0, am1, am2, am3);
        *(float4*)(out_v + (size_t)node * DOUT + l * 4) = make_float4(av0, av1, av2, av3);
    }
}

// ---------------------------------------------------------------------------
extern "C" void kernel_launch(void* const* d_in, const int* in_sizes, int n_in,
                              void* d_out, int out_size, void* d_ws, size_t ws_size,
                              hipStream_t stream) {
    const float* mean = (const float*)d_in[0];
    const float* var  = (const float*)d_in[1];
    const float* Wm   = (const float*)d_in[2];
    const float* bm   = (const float*)d_in[3];
    const float* Wv   = (const float*)d_in[4];
    const float* bv   = (const float*)d_in[5];
    const float* a0   = (const float*)d_in[6];
    const float* a1   = (const float*)d_in[7];
    const int*   es   = (const int*)d_in[8];
    const int*   ed   = (const int*)d_in[9];
    const int    E    = in_sizes[6];

    // Workspace layout (byte offsets, 16B-aligned; round-0 proven):
    //   mv [N][256] bf16           0          .. 25,600,000
    //   slots uint2[196*5120]      25,600,000 .. 33,628,160
    //   final_e uint2[E]           33,628,160 .. 40,028,160
    //   node_start int[N+1]        40,028,160 .. 40,228,164
    //   gcur int[196]              40,228,176 .. 40,228,960
    //   wfm/wfv bf16 frags         40,228,976 .. 40,294,512
    char* ws = (char*)d_ws;
    ushort_t* mv        = (ushort_t*)ws;
    uint2* slots        = (uint2*)(ws + 25600000);
    uint2* final_e      = (uint2*)(ws + 33628160);
    int*   node_start   = (int*)  (ws + 40028160);
    int*   gcur         = (int*)  (ws + 40228176);
    ushort_t* wfm       = (ushort_t*)(ws + 40228976);
    ushort_t* wfv       = wfm + 16384;

    float* out_m = (float*)d_out;
    float* out_v = out_m + (size_t)N_NODES * DOUT;

    prep_w_kernel<<<64, 256, 0, stream>>>(Wm, Wv, wfm, wfv, gcur);

    const int nA = (E + EPB - 1) / EPB;
    fused_projA_kernel<<<nA + NB_PROJ, 256, 0, stream>>>(
        mean, var, bm, bv, wfm, wfv, mv,
        es, ed, a0, a1, gcur, slots, E, nA);

    place_kernel<<<NBKT, 1024, 0, stream>>>(
        gcur, slots, final_e, node_start);

    agg_kernel<<<(N_NODES + 3) / 4, 256, 0, stream>>>(
        mv, final_e, node_start, out_m, out_v);
}